// Round 11
// baseline (211.871 us; speedup 1.0000x reference)
//
#include <hip/hip_runtime.h>
#include <hip/hip_fp16.h>
#include <math.h>

#define N_NODES 100000
#define N_EDGES 3200000

// Coarse-bucketed counting sort: 512 nodes per bucket.
#define NPBC  512
#define NBC   196            // ceil(100000/512)
#define KB2   512            // partition blocks
#define CH2   6250           // edges per partition block (N_EDGES / KB2)

// h2 row stride in halfs: 24B rows (11 values + 1 pad), 8B-aligned.
// Table = 2.4MB < 4MB XCD L2 (and producer writes are NT, so the read table
// keeps L2 residency). Row load = uint4 + uint2 (2 requests; ~1/8 straddle).
#define HS    12

// Native clang vector types for nontemporal builtins (HIP_vector_type is
// rejected by __builtin_nontemporal_store).
typedef unsigned int v4u __attribute__((ext_vector_type(4)));
typedef unsigned int v2u __attribute__((ext_vector_type(2)));

__device__ __forceinline__ float gelu_tanh(float x) {
    // jax.nn.gelu default approximate=True (tanh form)
    const float c = 0.7978845608028654f;  // sqrt(2/pi)
    float t = tanhf(c * (x + 0.044715f * x * x * x));
    return 0.5f * x * (1.0f + t);
}

// Distinguish int64 vs int32 edge_index layout: under little-endian int64 with
// values in [0, 1e5), every odd dword is 0. Under int32 these are random src
// values; P(all 64 == 0) ~ 0.
__global__ void detect_kernel(const unsigned int* __restrict__ ei, int* __restrict__ flag) {
    unsigned int v = ei[2 * threadIdx.x + 1];
    unsigned long long m = __ballot(v != 0u);
    if (threadIdx.x == 0) flag[0] = (m != 0ull) ? 1 : 0;  // 1 => int32 layout
}

__device__ __forceinline__ int load_idx(const void* ei, int f, size_t pos) {
    if (f) return __builtin_nontemporal_load((const int*)ei + pos);
    return (int)__builtin_nontemporal_load((const long long*)ei + pos);
}

// Pass A: per-block coarse-bucket histogram -> bcnt[b*KB2 + k].
__global__ void cnt_kernel(const void* __restrict__ ei, const int* __restrict__ flag,
                           int* __restrict__ bcnt) {
    __shared__ int lcnt[NBC];
    int k = blockIdx.x, t = threadIdx.x;
    for (int b = t; b < NBC; b += 256) lcnt[b] = 0;
    __syncthreads();
    int f = flag[0];
    int lo = k * CH2, hi = min(lo + CH2, N_EDGES);
    for (int e = lo + t; e < hi; e += 256) {
        int d = load_idx(ei, f, (size_t)N_EDGES + e);
        atomicAdd(&lcnt[d >> 9], 1);
    }
    __syncthreads();
    for (int b = t; b < NBC; b += 256) bcnt[b * KB2 + k] = lcnt[b];
}

// Pass B1: per-bucket exclusive prefix over blocks, in place; tot[b] = sum.
__global__ void bprefix_kernel(int* __restrict__ bcnt, int* __restrict__ tot) {
    int b = blockIdx.x * blockDim.x + threadIdx.x;
    if (b >= NBC) return;
    int run = 0;
    int base = b * KB2;
    for (int k = 0; k < KB2; k++) {
        int v = bcnt[base + k];
        bcnt[base + k] = run;
        run += v;
    }
    tot[b] = run;
}

// Pass B2: exclusive scan over bucket totals -> bbase; off[N] = E.
__global__ void bscan_kernel(const int* __restrict__ tot, int* __restrict__ bbase,
                             int* __restrict__ off) {
    __shared__ int sh[256];
    int t = threadIdx.x;
    int v = (t < NBC) ? tot[t] : 0;
    sh[t] = v;
    __syncthreads();
    int val = v;
    for (int o = 1; o < 256; o <<= 1) {
        int add = (t >= o) ? sh[t - o] : 0;
        __syncthreads();
        val += add;
        sh[t] = val;
        __syncthreads();
    }
    if (t < NBC) bbase[t] = val - v;
    if (t == NBC - 1) off[N_NODES] = val;  // == N_EDGES
}

// Pass C: place each edge in its block's pre-claimed range (no global atomics).
// Packed entry = src | local_dst<<17  (src 17 bits, local 9 bits).
__global__ void part2_kernel(const void* __restrict__ ei, const int* __restrict__ flag,
                             const int* __restrict__ boff, const int* __restrict__ bbase,
                             int* __restrict__ btmp) {
    __shared__ int lcnt[NBC];
    __shared__ int lbase[NBC];
    int k = blockIdx.x, t = threadIdx.x;
    for (int b = t; b < NBC; b += 256) {
        lcnt[b] = 0;
        lbase[b] = bbase[b] + boff[b * KB2 + k];
    }
    __syncthreads();
    int f = flag[0];
    int lo = k * CH2, hi = min(lo + CH2, N_EDGES);
    for (int e = lo + t; e < hi; e += 256) {
        int s = load_idx(ei, f, e);
        int d = load_idx(ei, f, (size_t)N_EDGES + e);
        int b = d >> 9;
        int pos = atomicAdd(&lcnt[b], 1);
        btmp[lbase[b] + pos] = s | ((d & (NPBC - 1)) << 17);
    }
}

// Pass D: one block per coarse bucket. LDS histogram over 512 local nodes +
// scan -> off/dinv; then direct scatter into the block's own csr segment.
__global__ void build2_kernel(const int* __restrict__ tot, const int* __restrict__ bbase,
                              const int* __restrict__ btmp, int* __restrict__ csr,
                              int* __restrict__ off, float* __restrict__ dinv) {
    __shared__ int lcnt[NPBC];
    __shared__ int lcur[NPBC];
    __shared__ int ssc[NPBC];
    int b = blockIdx.x;
    int t = threadIdx.x;   // 0..511, == local node id
    int cnt = tot[b];
    int base = bbase[b];
    lcnt[t] = 0;
    __syncthreads();
    const int* bt = btmp + base;
    for (int i = t; i < cnt; i += NPBC) atomicAdd(&lcnt[bt[i] >> 17], 1);
    __syncthreads();
    int c = lcnt[t];
    ssc[t] = c;
    __syncthreads();
    int val = c;
    for (int o = 1; o < NPBC; o <<= 1) {
        int add = (t >= o) ? ssc[t - o] : 0;
        __syncthreads();
        val += add;
        ssc[t] = val;
        __syncthreads();
    }
    int excl = val - c;
    lcur[t] = excl;
    int node = b * NPBC + t;
    if (node < N_NODES) {
        off[node] = base + excl;
        dinv[node] = rsqrtf((float)c + 1.0f);  // +1 = appended self-loop
    }
    __syncthreads();
    for (int i = t; i < cnt; i += NPBC) {
        int e = bt[i];
        int p = atomicAdd(&lcur[e >> 17], 1);
        csr[base + p] = e & 0x1FFFF;
    }
}

// Accumulate one fp16 h2 row (stride 12 halfs = 24B, 8B-aligned) into
// a[0..10]. Two memory requests: 16B + 8B.
__device__ __forceinline__ void acc_row(const __half* __restrict__ h2, int n, float* a) {
    const __half* r = h2 + (size_t)n * HS;
    v4u u = *(const v4u*)r;
    v2u v = *(const v2u*)(r + 8);
    union { unsigned int u; __half2 h; } cv;
    float2 f;
    cv.u = u.x; f = __half22float2(cv.h); a[0] += f.x; a[1] += f.y;
    cv.u = u.y; f = __half22float2(cv.h); a[2] += f.x; a[3] += f.y;
    cv.u = u.z; f = __half22float2(cv.h); a[4] += f.x; a[5] += f.y;
    cv.u = u.w; f = __half22float2(cv.h); a[6] += f.x; a[7] += f.y;
    cv.u = v.x; f = __half22float2(cv.h); a[8] += f.x; a[9] += f.y;
    cv.u = v.y; f = __half22float2(cv.h); a[10] += f.x;
}

// Gather a node's neighbor rows with software-pipelined index prefetch.
// 8 lanes per node (p = lane phase 0..7), stride-8 edge walk. csr reads are
// non-temporal so the streaming index array doesn't evict the h2 table.
__device__ __forceinline__ void gather8(const int* __restrict__ csr, int lo, int hi, int p,
                                        const __half* __restrict__ h2in, float* a) {
    int e = lo + p;
    if (e >= hi) return;
    int s = __builtin_nontemporal_load(csr + e);
    for (e += 8; e < hi; e += 8) {
        int s_next = __builtin_nontemporal_load(csr + e);
        acc_row(h2in, s, a);
        s = s_next;
    }
    acc_row(h2in, s, a);
}

// NT store of one packed h2 row from a __half[HS] register array (24B).
__device__ __forceinline__ void store_row_nt(__half* __restrict__ dst_row,
                                             const __half* __restrict__ r) {
    __builtin_nontemporal_store(*(const v4u*)r, (v4u*)dst_row);
    __builtin_nontemporal_store(*(const v2u*)(r + 8), (v2u*)(dst_row + 8));
}

// Layer 1 pre-propagation: h2[n] = fp16( dinv[n] * (X[n] @ W1) ), stride HS.
__global__ void node1_kernel(const float* __restrict__ X, const float* __restrict__ W,
                             const float* __restrict__ dinv, __half* __restrict__ h2) {
    int n = blockIdx.x * blockDim.x + threadIdx.x;
    if (n >= N_NODES) return;
    float x[11];
#pragma unroll
    for (int i = 0; i < 11; i++) x[i] = X[n * 11 + i];
    float di = dinv[n];
    __half r[HS];
#pragma unroll
    for (int j = 0; j < 11; j++) {
        float a = 0.0f;
#pragma unroll
        for (int i = 0; i < 11; i++) a += x[i] * W[i * 11 + j];
        r[j] = __float2half(di * a);
    }
    r[11] = __float2half(0.0f);
    store_row_nt(h2 + (size_t)n * HS, r);
}

// Fused gather + finalize + gelu + next-layer GEMM. 8 lanes per node.
// h2out writes are non-temporal: the write stream must not evict the h2in
// table from L2 (it is re-read ~64x per line during this kernel).
template <int OUT>
__global__ void mid_kernel(const int* __restrict__ off, const int* __restrict__ csr,
                           const __half* __restrict__ h2in, const float* __restrict__ bias,
                           const float* __restrict__ W, const float* __restrict__ dinv,
                           __half* __restrict__ h2out) {
    int tid = blockIdx.x * blockDim.x + threadIdx.x;
    int n = tid >> 3;
    int p = tid & 7;
    if (n >= N_NODES) return;
    int lo = off[n], hi = off[n + 1];
    float a[11];
#pragma unroll
    for (int i = 0; i < 11; i++) a[i] = 0.0f;
    if (p == 0) acc_row(h2in, n, a);  // self-loop term
    gather8(csr, lo, hi, p, h2in, a);
#pragma unroll
    for (int i = 0; i < 11; i++) {
        a[i] += __shfl_xor(a[i], 1);
        a[i] += __shfl_xor(a[i], 2);
        a[i] += __shfl_xor(a[i], 4);
    }
    float di = dinv[n];
    float t[11];
#pragma unroll
    for (int i = 0; i < 11; i++) t[i] = gelu_tanh(di * a[i] + bias[i]);
    // 12 output slots over 8 lanes: j = p (all) and j = p+8 (p<4).
#pragma unroll
    for (int j0 = 0; j0 < 2; j0++) {
        int j = p + 8 * j0;
        if (j >= HS) continue;
        float o = 0.0f;
        if (j < OUT) {
            float acc = 0.0f;
#pragma unroll
            for (int i = 0; i < 11; i++) acc += t[i] * W[i * OUT + j];
            o = di * acc;
        }
        __builtin_nontemporal_store(__half_as_ushort(__float2half(o)),
                                    (unsigned short*)(h2out + (size_t)n * HS + j));
    }
}

// Final layer: gather + finalize + log_softmax (10 classes). 8 lanes per node.
__global__ void final_kernel(const int* __restrict__ off, const int* __restrict__ csr,
                             const __half* __restrict__ h2in, const float* __restrict__ bias,
                             const float* __restrict__ dinv, float* __restrict__ out) {
    int tid = blockIdx.x * blockDim.x + threadIdx.x;
    int n = tid >> 3;
    int p = tid & 7;
    if (n >= N_NODES) return;
    int lo = off[n], hi = off[n + 1];
    float a[11];
#pragma unroll
    for (int i = 0; i < 11; i++) a[i] = 0.0f;
    if (p == 0) acc_row(h2in, n, a);
    gather8(csr, lo, hi, p, h2in, a);
#pragma unroll
    for (int i = 0; i < 10; i++) {
        a[i] += __shfl_xor(a[i], 1);
        a[i] += __shfl_xor(a[i], 2);
        a[i] += __shfl_xor(a[i], 4);
    }
    float di = dinv[n];
    float t[10];
    float m = -1e30f;
#pragma unroll
    for (int j = 0; j < 10; j++) {
        t[j] = di * a[j] + bias[j];
        m = fmaxf(m, t[j]);
    }
    float s = 0.0f;
#pragma unroll
    for (int j = 0; j < 10; j++) s += expf(t[j] - m);
    float ls = logf(s);
    for (int j = p; j < 10; j += 8)
        __builtin_nontemporal_store(t[j] - m - ls, out + (size_t)n * 10 + j);
}

extern "C" void kernel_launch(void* const* d_in, const int* in_sizes, int n_in,
                              void* d_out, int out_size, void* d_ws, size_t ws_size,
                              hipStream_t stream) {
    const float* X  = (const float*)d_in[0];
    const void*  ei = d_in[1];
    const float* W1 = (const float*)d_in[2];
    const float* b1 = (const float*)d_in[3];
    const float* W2 = (const float*)d_in[4];
    const float* b2 = (const float*)d_in[5];
    const float* W3 = (const float*)d_in[6];
    const float* b3 = (const float*)d_in[7];
    float* out = (float*)d_out;

    const size_t N = N_NODES;
    const size_t E = N_EDGES;
    // Workspace layout (regions kept 16B-aligned).
    __half* h2a = (__half*)d_ws;                // [HS*N] halfs (2.4 MB)
    __half* h2b = h2a + (size_t)HS * N;         // [HS*N] halfs
    int*   csr  = (int*)(h2b + (size_t)HS * N); // [E]
    int*   btmp = csr + E;                      // [E]
    int*   bcnt = btmp + E;                     // [NBC*KB2] (becomes boff in place)
    int*   tot  = bcnt + (size_t)NBC * KB2;     // [NBC+4 pad]
    int*   bbase= tot + NBC + 4;                // [NBC+4 pad]
    int*   off  = bbase + NBC + 4;              // [N+4]
    float* dinv = (float*)(off + N + 4);        // [N]
    int*   flag = (int*)(dinv + N);             // [1]

    const int nb = (N_NODES + 255) / 256;
    const int gb8 = (8 * N_NODES + 255) / 256;

    detect_kernel<<<1, 64, 0, stream>>>((const unsigned int*)ei, flag);
    cnt_kernel<<<KB2, 256, 0, stream>>>(ei, flag, bcnt);
    bprefix_kernel<<<(NBC + 63) / 64, 64, 0, stream>>>(bcnt, tot);
    bscan_kernel<<<1, 256, 0, stream>>>(tot, bbase, off);
    part2_kernel<<<KB2, 256, 0, stream>>>(ei, flag, bcnt, bbase, btmp);
    build2_kernel<<<NBC, NPBC, 0, stream>>>(tot, bbase, btmp, csr, off, dinv);

    node1_kernel<<<nb, 256, 0, stream>>>(X, W1, dinv, h2a);
    mid_kernel<11><<<gb8, 256, 0, stream>>>(off, csr, h2a, b1, W2, dinv, h2b);
    mid_kernel<10><<<gb8, 256, 0, stream>>>(off, csr, h2b, b2, W3, dinv, h2a);
    final_kernel<<<gb8, 256, 0, stream>>>(off, csr, h2a, b3, dinv, out);
}

// Round 12
// 163.350 us; speedup vs baseline: 1.2970x; 1.2970x over previous
//
#include <hip/hip_runtime.h>
#include <hip/hip_fp16.h>
#include <math.h>

#define N_NODES 100000
#define N_EDGES 3200000

// Coarse-bucketed counting sort: 512 nodes per bucket.
#define NPBC  512
#define NBC   196            // ceil(100000/512)
#define KB2   512            // partition blocks
#define CH2   6250           // edges per partition block (N_EDGES / KB2)

// h2 row stride in halfs: 24B rows (11 values + 1 pad), 8B-aligned.
// Table = 2.4MB, L2-resident. Row load = uint4+uint2 (2 requests, ~7/8 of
// rows touch a single 64B line).
#define HS    12

__device__ __forceinline__ float gelu_tanh(float x) {
    // jax.nn.gelu default approximate=True (tanh form)
    const float c = 0.7978845608028654f;  // sqrt(2/pi)
    float t = tanhf(c * (x + 0.044715f * x * x * x));
    return 0.5f * x * (1.0f + t);
}

// Distinguish int64 vs int32 edge_index layout: under little-endian int64 with
// values in [0, 1e5), every odd dword is 0. Under int32 these are random src
// values; P(all 64 == 0) ~ 0.
__global__ void detect_kernel(const unsigned int* __restrict__ ei, int* __restrict__ flag) {
    unsigned int v = ei[2 * threadIdx.x + 1];
    unsigned long long m = __ballot(v != 0u);
    if (threadIdx.x == 0) flag[0] = (m != 0ull) ? 1 : 0;  // 1 => int32 layout
}

__device__ __forceinline__ int load_idx(const void* ei, int f, size_t pos) {
    if (f) return ((const int*)ei)[pos];
    return (int)((const long long*)ei)[pos];
}

// Pass A: per-block coarse-bucket histogram -> bcnt[b*KB2 + k].
__global__ void cnt_kernel(const void* __restrict__ ei, const int* __restrict__ flag,
                           int* __restrict__ bcnt) {
    __shared__ int lcnt[NBC];
    int k = blockIdx.x, t = threadIdx.x;
    for (int b = t; b < NBC; b += 256) lcnt[b] = 0;
    __syncthreads();
    int f = flag[0];
    int lo = k * CH2, hi = min(lo + CH2, N_EDGES);
    for (int e = lo + t; e < hi; e += 256) {
        int d = load_idx(ei, f, (size_t)N_EDGES + e);
        atomicAdd(&lcnt[d >> 9], 1);
    }
    __syncthreads();
    for (int b = t; b < NBC; b += 256) bcnt[b * KB2 + k] = lcnt[b];
}

// Pass B1: per-bucket exclusive prefix over blocks, in place; tot[b] = sum.
__global__ void bprefix_kernel(int* __restrict__ bcnt, int* __restrict__ tot) {
    int b = blockIdx.x * blockDim.x + threadIdx.x;
    if (b >= NBC) return;
    int run = 0;
    int base = b * KB2;
    for (int k = 0; k < KB2; k++) {
        int v = bcnt[base + k];
        bcnt[base + k] = run;
        run += v;
    }
    tot[b] = run;
}

// Pass B2: exclusive scan over bucket totals -> bbase; off[N] = E.
__global__ void bscan_kernel(const int* __restrict__ tot, int* __restrict__ bbase,
                             int* __restrict__ off) {
    __shared__ int sh[256];
    int t = threadIdx.x;
    int v = (t < NBC) ? tot[t] : 0;
    sh[t] = v;
    __syncthreads();
    int val = v;
    for (int o = 1; o < 256; o <<= 1) {
        int add = (t >= o) ? sh[t - o] : 0;
        __syncthreads();
        val += add;
        sh[t] = val;
        __syncthreads();
    }
    if (t < NBC) bbase[t] = val - v;
    if (t == NBC - 1) off[N_NODES] = val;  // == N_EDGES
}

// Pass C: place each edge in its block's pre-claimed range (no global atomics).
// Packed entry = src | local_dst<<17  (src 17 bits, local 9 bits).
__global__ void part2_kernel(const void* __restrict__ ei, const int* __restrict__ flag,
                             const int* __restrict__ boff, const int* __restrict__ bbase,
                             int* __restrict__ btmp) {
    __shared__ int lcnt[NBC];
    __shared__ int lbase[NBC];
    int k = blockIdx.x, t = threadIdx.x;
    for (int b = t; b < NBC; b += 256) {
        lcnt[b] = 0;
        lbase[b] = bbase[b] + boff[b * KB2 + k];
    }
    __syncthreads();
    int f = flag[0];
    int lo = k * CH2, hi = min(lo + CH2, N_EDGES);
    for (int e = lo + t; e < hi; e += 256) {
        int s = load_idx(ei, f, e);
        int d = load_idx(ei, f, (size_t)N_EDGES + e);
        int b = d >> 9;
        int pos = atomicAdd(&lcnt[b], 1);
        btmp[lbase[b] + pos] = s | ((d & (NPBC - 1)) << 17);
    }
}

// Pass D: one block per coarse bucket. LDS histogram over 512 local nodes +
// scan -> off/dinv; then direct scatter into the block's own csr segment.
__global__ void build2_kernel(const int* __restrict__ tot, const int* __restrict__ bbase,
                              const int* __restrict__ btmp, int* __restrict__ csr,
                              int* __restrict__ off, float* __restrict__ dinv) {
    __shared__ int lcnt[NPBC];
    __shared__ int lcur[NPBC];
    __shared__ int ssc[NPBC];
    int b = blockIdx.x;
    int t = threadIdx.x;   // 0..511, == local node id
    int cnt = tot[b];
    int base = bbase[b];
    lcnt[t] = 0;
    __syncthreads();
    const int* bt = btmp + base;
    for (int i = t; i < cnt; i += NPBC) atomicAdd(&lcnt[bt[i] >> 17], 1);
    __syncthreads();
    int c = lcnt[t];
    ssc[t] = c;
    __syncthreads();
    int val = c;
    for (int o = 1; o < NPBC; o <<= 1) {
        int add = (t >= o) ? ssc[t - o] : 0;
        __syncthreads();
        val += add;
        ssc[t] = val;
        __syncthreads();
    }
    int excl = val - c;
    lcur[t] = excl;
    int node = b * NPBC + t;
    if (node < N_NODES) {
        off[node] = base + excl;
        dinv[node] = rsqrtf((float)c + 1.0f);  // +1 = appended self-loop
    }
    __syncthreads();
    for (int i = t; i < cnt; i += NPBC) {
        int e = bt[i];
        int p = atomicAdd(&lcur[e >> 17], 1);
        csr[base + p] = e & 0x1FFFF;
    }
}

// Accumulate one fp16 h2 row (stride 12 halfs = 24B, 8B-aligned) into
// a[0..10]. Two memory requests: 16B (halfs 0..7) + 8B (halfs 8..11).
__device__ __forceinline__ void acc_row(const __half* __restrict__ h2, int n, float* a) {
    const __half* r = h2 + (size_t)n * HS;
    uint4 u = *(const uint4*)r;          // dwordx4 (dword alignment suffices)
    uint2 v = *(const uint2*)(r + 8);
    union { unsigned int u; __half2 h; } cv;
    float2 f;
    cv.u = u.x; f = __half22float2(cv.h); a[0] += f.x; a[1] += f.y;
    cv.u = u.y; f = __half22float2(cv.h); a[2] += f.x; a[3] += f.y;
    cv.u = u.z; f = __half22float2(cv.h); a[4] += f.x; a[5] += f.y;
    cv.u = u.w; f = __half22float2(cv.h); a[6] += f.x; a[7] += f.y;
    cv.u = v.x; f = __half22float2(cv.h); a[8] += f.x; a[9] += f.y;
    cv.u = v.y; f = __half22float2(cv.h); a[10] += f.x;
}

// Gather a node's neighbor rows with software-pipelined index prefetch.
// 8 lanes per node (p = lane phase 0..7), stride-8 edge walk.
__device__ __forceinline__ void gather8(const int* __restrict__ csr, int lo, int hi, int p,
                                        const __half* __restrict__ h2in, float* a) {
    int e = lo + p;
    if (e >= hi) return;
    int s = csr[e];
    for (e += 8; e < hi; e += 8) {
        int s_next = csr[e];
        acc_row(h2in, s, a);
        s = s_next;
    }
    acc_row(h2in, s, a);
}

// Layer 1 pre-propagation: h2[n] = fp16( dinv[n] * (X[n] @ W1) ), stride HS.
__global__ void node1_kernel(const float* __restrict__ X, const float* __restrict__ W,
                             const float* __restrict__ dinv, __half* __restrict__ h2) {
    int n = blockIdx.x * blockDim.x + threadIdx.x;
    if (n >= N_NODES) return;
    float x[11];
#pragma unroll
    for (int i = 0; i < 11; i++) x[i] = X[n * 11 + i];
    float di = dinv[n];
#pragma unroll
    for (int j = 0; j < 11; j++) {
        float a = 0.0f;
#pragma unroll
        for (int i = 0; i < 11; i++) a += x[i] * W[i * 11 + j];
        h2[(size_t)n * HS + j] = __float2half(di * a);
    }
    h2[(size_t)n * HS + 11] = __float2half(0.0f);
}

// Fused gather + finalize + gelu + next-layer GEMM. 8 lanes per node.
template <int OUT>
__global__ void mid_kernel(const int* __restrict__ off, const int* __restrict__ csr,
                           const __half* __restrict__ h2in, const float* __restrict__ bias,
                           const float* __restrict__ W, const float* __restrict__ dinv,
                           __half* __restrict__ h2out) {
    int tid = blockIdx.x * blockDim.x + threadIdx.x;
    int n = tid >> 3;
    int p = tid & 7;
    if (n >= N_NODES) return;
    int lo = off[n], hi = off[n + 1];
    float a[11];
#pragma unroll
    for (int i = 0; i < 11; i++) a[i] = 0.0f;
    if (p == 0) acc_row(h2in, n, a);  // self-loop term
    gather8(csr, lo, hi, p, h2in, a);
#pragma unroll
    for (int i = 0; i < 11; i++) {
        a[i] += __shfl_xor(a[i], 1);
        a[i] += __shfl_xor(a[i], 2);
        a[i] += __shfl_xor(a[i], 4);
    }
    float di = dinv[n];
    float t[11];
#pragma unroll
    for (int i = 0; i < 11; i++) t[i] = gelu_tanh(di * a[i] + bias[i]);
    // 12 output slots over 8 lanes: j = p (all) and j = p+8 (p<4).
#pragma unroll
    for (int j0 = 0; j0 < 2; j0++) {
        int j = p + 8 * j0;
        if (j >= HS) continue;
        float o = 0.0f;
        if (j < OUT) {
            float acc = 0.0f;
#pragma unroll
            for (int i = 0; i < 11; i++) acc += t[i] * W[i * OUT + j];
            o = di * acc;
        }
        h2out[(size_t)n * HS + j] = __float2half(o);
    }
}

// Final layer: gather + finalize + log_softmax (10 classes). 8 lanes per node.
__global__ void final_kernel(const int* __restrict__ off, const int* __restrict__ csr,
                             const __half* __restrict__ h2in, const float* __restrict__ bias,
                             const float* __restrict__ dinv, float* __restrict__ out) {
    int tid = blockIdx.x * blockDim.x + threadIdx.x;
    int n = tid >> 3;
    int p = tid & 7;
    if (n >= N_NODES) return;
    int lo = off[n], hi = off[n + 1];
    float a[11];
#pragma unroll
    for (int i = 0; i < 11; i++) a[i] = 0.0f;
    if (p == 0) acc_row(h2in, n, a);
    gather8(csr, lo, hi, p, h2in, a);
#pragma unroll
    for (int i = 0; i < 10; i++) {
        a[i] += __shfl_xor(a[i], 1);
        a[i] += __shfl_xor(a[i], 2);
        a[i] += __shfl_xor(a[i], 4);
    }
    float di = dinv[n];
    float t[10];
    float m = -1e30f;
#pragma unroll
    for (int j = 0; j < 10; j++) {
        t[j] = di * a[j] + bias[j];
        m = fmaxf(m, t[j]);
    }
    float s = 0.0f;
#pragma unroll
    for (int j = 0; j < 10; j++) s += expf(t[j] - m);
    float ls = logf(s);
    for (int j = p; j < 10; j += 8) out[(size_t)n * 10 + j] = t[j] - m - ls;
}

extern "C" void kernel_launch(void* const* d_in, const int* in_sizes, int n_in,
                              void* d_out, int out_size, void* d_ws, size_t ws_size,
                              hipStream_t stream) {
    const float* X  = (const float*)d_in[0];
    const void*  ei = d_in[1];
    const float* W1 = (const float*)d_in[2];
    const float* b1 = (const float*)d_in[3];
    const float* W2 = (const float*)d_in[4];
    const float* b2 = (const float*)d_in[5];
    const float* W3 = (const float*)d_in[6];
    const float* b3 = (const float*)d_in[7];
    float* out = (float*)d_out;

    const size_t N = N_NODES;
    const size_t E = N_EDGES;
    // Workspace layout (regions kept 16B-aligned).
    __half* h2a = (__half*)d_ws;                // [HS*N] halfs (2.4 MB)
    __half* h2b = h2a + (size_t)HS * N;         // [HS*N] halfs
    int*   csr  = (int*)(h2b + (size_t)HS * N); // [E]
    int*   btmp = csr + E;                      // [E]
    int*   bcnt = btmp + E;                     // [NBC*KB2] (becomes boff in place)
    int*   tot  = bcnt + (size_t)NBC * KB2;     // [NBC+4 pad]
    int*   bbase= tot + NBC + 4;                // [NBC+4 pad]
    int*   off  = bbase + NBC + 4;              // [N+4]
    float* dinv = (float*)(off + N + 4);        // [N]
    int*   flag = (int*)(dinv + N);             // [1]

    const int nb = (N_NODES + 255) / 256;
    const int gb8 = (8 * N_NODES + 255) / 256;

    detect_kernel<<<1, 64, 0, stream>>>((const unsigned int*)ei, flag);
    cnt_kernel<<<KB2, 256, 0, stream>>>(ei, flag, bcnt);
    bprefix_kernel<<<(NBC + 63) / 64, 64, 0, stream>>>(bcnt, tot);
    bscan_kernel<<<1, 256, 0, stream>>>(tot, bbase, off);
    part2_kernel<<<KB2, 256, 0, stream>>>(ei, flag, bcnt, bbase, btmp);
    build2_kernel<<<NBC, NPBC, 0, stream>>>(tot, bbase, btmp, csr, off, dinv);

    node1_kernel<<<nb, 256, 0, stream>>>(X, W1, dinv, h2a);
    mid_kernel<11><<<gb8, 256, 0, stream>>>(off, csr, h2a, b1, W2, dinv, h2b);
    mid_kernel<10><<<gb8, 256, 0, stream>>>(off, csr, h2b, b2, W3, dinv, h2a);
    final_kernel<<<gb8, 256, 0, stream>>>(off, csr, h2a, b3, dinv, out);
}